// Round 2
// baseline (344.695 us; speedup 1.0000x reference)
//
#include <hip/hip_runtime.h>
#include <hip/hip_bf16.h>

// Problem constants
#define Bc 2
#define Sc 2048
#define Dc 1024
#define Hc 16
#define DKc 64
#define Mrows 4096  // B*S

typedef __bf16 bf16;
typedef __bf16 bf16x8 __attribute__((ext_vector_type(8)));
typedef __bf16 bf16x4 __attribute__((ext_vector_type(4)));
typedef float f32x4 __attribute__((ext_vector_type(4)));

// ---------------- fp32 -> bf16 conversion ----------------
__global__ void cvt_f32_bf16(const float* __restrict__ in, bf16* __restrict__ out, int n) {
    int idx = (blockIdx.x * blockDim.x + threadIdx.x) * 4;
    if (idx < n) {
        float4 v = *(const float4*)(in + idx);
        bf16x4 o = { (bf16)v.x, (bf16)v.y, (bf16)v.z, (bf16)v.w };
        *(bf16x4*)(out + idx) = o;
    }
}

// ---------------- GEMM: C[M,N] = A[M,K] * Bt[N,K]^T ----------------
// 128x128 block tile, 256 threads (4 waves in 2x2), 16x16x32 bf16 MFMA.
#define LDT 56  // LDS row stride in bf16 elems (112B: 16B-aligned, 2-way bank pattern)
template <typename OutT>
__global__ __launch_bounds__(256) void gemm_bt(const bf16* __restrict__ A,
                                               const bf16* __restrict__ Bt,
                                               OutT* __restrict__ C,
                                               int M, int N, int K) {
    __shared__ bf16 As[128 * LDT];
    __shared__ bf16 Bs[128 * LDT];
    const int tid = threadIdx.x;
    const int bm = blockIdx.y * 128, bn = blockIdx.x * 128;
    const int w = tid >> 6, l = tid & 63;
    const int wr = w >> 1, wc = w & 1;
    const int lr = l & 15, lk = (l >> 4) * 8;

    f32x4 acc[4][4] = {};

    const int srow = tid >> 2;         // 0..63
    const int skoff = (tid & 3) * 8;   // 0,8,16,24
    const bf16* Arow = A + (size_t)(bm + srow) * K + skoff;
    const bf16* Brow = Bt + (size_t)(bn + srow) * K + skoff;

    for (int k0 = 0; k0 < K; k0 += 32) {
        __syncthreads();
        *(bf16x8*)&As[srow * LDT + skoff]        = *(const bf16x8*)(Arow + k0);
        *(bf16x8*)&As[(srow + 64) * LDT + skoff] = *(const bf16x8*)(Arow + (size_t)64 * K + k0);
        *(bf16x8*)&Bs[srow * LDT + skoff]        = *(const bf16x8*)(Brow + k0);
        *(bf16x8*)&Bs[(srow + 64) * LDT + skoff] = *(const bf16x8*)(Brow + (size_t)64 * K + k0);
        __syncthreads();

        bf16x8 af[4], bfr[4];
#pragma unroll
        for (int i = 0; i < 4; i++) af[i]  = *(bf16x8*)&As[(wr * 64 + i * 16 + lr) * LDT + lk];
#pragma unroll
        for (int j = 0; j < 4; j++) bfr[j] = *(bf16x8*)&Bs[(wc * 64 + j * 16 + lr) * LDT + lk];
#pragma unroll
        for (int i = 0; i < 4; i++)
#pragma unroll
            for (int j = 0; j < 4; j++)
                acc[i][j] = __builtin_amdgcn_mfma_f32_16x16x32_bf16(af[i], bfr[j], acc[i][j], 0, 0, 0);
    }

    // C/D layout: col = lane&15, row = (lane>>4)*4 + reg
    const int cr = (l >> 4) * 4, cc = l & 15;
#pragma unroll
    for (int i = 0; i < 4; i++)
#pragma unroll
        for (int j = 0; j < 4; j++)
#pragma unroll
            for (int r = 0; r < 4; r++) {
                int row = bm + wr * 64 + i * 16 + cr + r;
                int col = bn + wc * 64 + j * 16 + cc;
                C[(size_t)row * N + col] = (OutT)acc[i][j][r];
            }
}

// ---------------- RoPE (in place, on (B,S,H,DK) == (B,S,D) layout) ----------------
__global__ void rope_k(bf16* __restrict__ Q, bf16* __restrict__ K) {
    int i = blockIdx.x * blockDim.x + threadIdx.x;  // over B*S*H*(DK/2) = 2^21
    int pair = i & 31;
    int h = (i >> 5) & 15;
    int s = (i >> 9) & 2047;
    int b = i >> 20;
    float inv_freq = __powf(10000.0f, -((2.0f * pair) / 64.0f));
    float ang = (float)s * inv_freq;
    float c = cosf(ang), sn = sinf(ang);
    size_t base = ((size_t)(b * Sc + s)) * Dc + h * 64 + pair * 2;
    float q1 = (float)Q[base], q2 = (float)Q[base + 1];
    Q[base]     = (bf16)(q1 * c - q2 * sn);
    Q[base + 1] = (bf16)(q1 * sn + q2 * c);
    float k1 = (float)K[base], k2 = (float)K[base + 1];
    K[base]     = (bf16)(k1 * c - k2 * sn);
    K[base + 1] = (bf16)(k1 * sn + k2 * c);
}

// ---------------- causal flash attention ----------------
// Per block: one (b, h, 64 q-rows). 4 waves x 16 q-rows. K-tiles of 64.
#define LDA 72  // LDS row stride (144B: 16B-aligned, 2-way banks)
__global__ __launch_bounds__(256) void attn_k(const bf16* __restrict__ Q,
                                              const bf16* __restrict__ Kt,
                                              const bf16* __restrict__ V,
                                              bf16* __restrict__ Oa) {
    __shared__ bf16 Ks[64 * LDA];       // Ks[key][dk]
    __shared__ bf16 Vs[64 * LDA];       // Vs[dk][key]  (transposed)
    __shared__ bf16 Ps[4][16 * LDA];    // per-wave P in A-layout source

    const int bid = blockIdx.x;
    const int q0 = (bid & 31) * 64;
    const int h = (bid >> 5) & 15;
    const int b = bid >> 9;
    const int tid = threadIdx.x, w = tid >> 6, l = tid & 63;
    const int lr = l & 15, lc = l >> 4;

    const bf16* Qb = Q + ((size_t)b * Sc) * Dc + h * 64;
    const bf16* Kb = Kt + ((size_t)b * Sc) * Dc + h * 64;
    const bf16* Vb = V + ((size_t)b * Sc) * Dc + h * 64;

    // Q fragments (hoisted): wave rows q0 + w*16 + lr
    const int qrow = q0 + w * 16 + lr;
    bf16x8 qf0 = *(const bf16x8*)(Qb + (size_t)qrow * Dc + lc * 8);
    bf16x8 qf1 = *(const bf16x8*)(Qb + (size_t)qrow * Dc + 32 + lc * 8);

    f32x4 oacc[4] = {};
    float m[4], lsum[4];
#pragma unroll
    for (int r = 0; r < 4; r++) { m[r] = -1e30f; lsum[r] = 0.0f; }

    const int kend = q0 + 64;
    const int skey = tid >> 3;          // 0..31
    const int sdk = (tid & 7) * 8;
    const int vkey = tid & 63, vdk0 = (tid >> 6) * 16;

    for (int k0 = 0; k0 < kend; k0 += 64) {
        __syncthreads();
        // stage K (coalesced rows)
        *(bf16x8*)&Ks[skey * LDA + sdk]        = *(const bf16x8*)(Kb + (size_t)(k0 + skey) * Dc + sdk);
        *(bf16x8*)&Ks[(skey + 32) * LDA + sdk] = *(const bf16x8*)(Kb + (size_t)(k0 + skey + 32) * Dc + sdk);
        // stage V transposed
#pragma unroll
        for (int c = 0; c < 2; c++) {
            bf16x8 vv = *(const bf16x8*)(Vb + (size_t)(k0 + vkey) * Dc + vdk0 + c * 8);
#pragma unroll
            for (int e = 0; e < 8; e++) Vs[(vdk0 + c * 8 + e) * LDA + vkey] = vv[e];
        }
        __syncthreads();

        // S = Q K^T  (per wave: 16 q-rows x 64 keys)
        f32x4 sfr[4];
#pragma unroll
        for (int j = 0; j < 4; j++) {
            bf16x8 b0 = *(bf16x8*)&Ks[(j * 16 + lr) * LDA + lc * 8];
            bf16x8 b1 = *(bf16x8*)&Ks[(j * 16 + lr) * LDA + 32 + lc * 8];
            f32x4 z = {};
            z = __builtin_amdgcn_mfma_f32_16x16x32_bf16(qf0, b0, z, 0, 0, 0);
            z = __builtin_amdgcn_mfma_f32_16x16x32_bf16(qf1, b1, z, 0, 0, 0);
            sfr[j] = z;
        }

        // clip, causal mask, scale by 1/8; online softmax bookkeeping
        float tv[4][4], tmax[4];
#pragma unroll
        for (int r = 0; r < 4; r++) tmax[r] = -1e30f;
#pragma unroll
        for (int j = 0; j < 4; j++) {
            int kg = k0 + j * 16 + lr;
#pragma unroll
            for (int r = 0; r < 4; r++) {
                int qg = q0 + w * 16 + lc * 4 + r;
                float s = sfr[j][r];
                s = fminf(fmaxf(s, -80.0f), 80.0f) * 0.125f;
                if (kg > qg) s = -1e30f;
                tv[j][r] = s;
                tmax[r] = fmaxf(tmax[r], s);
            }
        }
#pragma unroll
        for (int d = 1; d < 16; d <<= 1)
#pragma unroll
            for (int r = 0; r < 4; r++) tmax[r] = fmaxf(tmax[r], __shfl_xor(tmax[r], d, 64));

        float fac[4], psum[4] = {0, 0, 0, 0};
#pragma unroll
        for (int r = 0; r < 4; r++) {
            float mn = fmaxf(m[r], tmax[r]);
            fac[r] = __expf(m[r] - mn);
            m[r] = mn;
        }
#pragma unroll
        for (int j = 0; j < 4; j++)
#pragma unroll
            for (int r = 0; r < 4; r++) {
                float p = __expf(tv[j][r] - m[r]);
                psum[r] += p;
                Ps[w][(lc * 4 + r) * LDA + j * 16 + lr] = (bf16)p;
            }
#pragma unroll
        for (int d = 1; d < 16; d <<= 1)
#pragma unroll
            for (int r = 0; r < 4; r++) psum[r] += __shfl_xor(psum[r], d, 64);
#pragma unroll
        for (int r = 0; r < 4; r++) lsum[r] = lsum[r] * fac[r] + psum[r];
#pragma unroll
        for (int j = 0; j < 4; j++)
#pragma unroll
            for (int r = 0; r < 4; r++) oacc[j][r] *= fac[r];

        __syncthreads();  // order Ps writes before Ps reads (uniform barrier)

        // O += P V  (A = P [16 x 64keys], B = V [64keys x 64dk])
#pragma unroll
        for (int c = 0; c < 2; c++) {
            bf16x8 pf = *(bf16x8*)&Ps[w][lr * LDA + c * 32 + lc * 8];
#pragma unroll
            for (int j = 0; j < 4; j++) {
                bf16x8 vf = *(bf16x8*)&Vs[(j * 16 + lr) * LDA + c * 32 + lc * 8];
                oacc[j] = __builtin_amdgcn_mfma_f32_16x16x32_bf16(pf, vf, oacc[j], 0, 0, 0);
            }
        }
    }

    // epilogue: divide by row sums, write att in (B,S,D) bf16
    bf16* Ob = Oa + ((size_t)b * Sc) * Dc + h * 64;
#pragma unroll
    for (int j = 0; j < 4; j++)
#pragma unroll
        for (int r = 0; r < 4; r++) {
            int qg = q0 + w * 16 + lc * 4 + r;
            float v = oacc[j][r] / lsum[r];
            Ob[(size_t)qg * Dc + j * 16 + lr] = (bf16)v;
        }
}

// ---------------- launcher ----------------
extern "C" void kernel_launch(void* const* d_in, const int* in_sizes, int n_in,
                              void* d_out, int out_size, void* d_ws, size_t ws_size,
                              hipStream_t stream) {
    const float* x  = (const float*)d_in[0];
    const float* Wq = (const float*)d_in[1];
    const float* Wk = (const float*)d_in[2];
    const float* Wv = (const float*)d_in[3];
    const float* Wo = (const float*)d_in[4];

    const int NX = Bc * Sc * Dc;   // 4,194,304
    const int NW = Dc * Dc;        // 1,048,576

    bf16* xb  = (bf16*)d_ws;
    bf16* wqb = xb + NX;
    bf16* wkb = wqb + NW;
    bf16* wvb = wkb + NW;
    bf16* wob = wvb + NW;
    bf16* Yq  = wob + NW;
    bf16* Yk  = Yq + NX;
    bf16* Yv  = Yk + NX;
    bf16* att = Yv + NX;
    // total: 25,165,824 bf16 elems = 48 MiB of d_ws

    cvt_f32_bf16<<<NX / 4 / 256, 256, 0, stream>>>(x, xb, NX);
    cvt_f32_bf16<<<NW / 4 / 256, 256, 0, stream>>>(Wq, wqb, NW);
    cvt_f32_bf16<<<NW / 4 / 256, 256, 0, stream>>>(Wk, wkb, NW);
    cvt_f32_bf16<<<NW / 4 / 256, 256, 0, stream>>>(Wv, wvb, NW);
    cvt_f32_bf16<<<NW / 4 / 256, 256, 0, stream>>>(Wo, wob, NW);

    dim3 gg(Dc / 128, Mrows / 128);  // (8, 32)
    gemm_bt<bf16><<<gg, 256, 0, stream>>>(xb, wqb, Yq, Mrows, Dc, Dc);
    gemm_bt<bf16><<<gg, 256, 0, stream>>>(xb, wkb, Yk, Mrows, Dc, Dc);
    gemm_bt<bf16><<<gg, 256, 0, stream>>>(xb, wvb, Yv, Mrows, Dc, Dc);

    rope_k<<<(Bc * Sc * Hc * 32) / 256, 256, 0, stream>>>(Yq, Yk);

    attn_k<<<Bc * Hc * (Sc / 64), 256, 0, stream>>>(Yq, Yk, Yv, att);

    gemm_bt<float><<<gg, 256, 0, stream>>>(att, wob, (float*)d_out, Mrows, Dc, Dc);
}

// Round 3
// 222.490 us; speedup vs baseline: 1.5493x; 1.5493x over previous
//
#include <hip/hip_runtime.h>
#include <hip/hip_bf16.h>

// Problem constants
#define Bc 2
#define Sc 2048
#define Dc 1024
#define Hc 16
#define DKc 64
#define Mrows 4096  // B*S

typedef __bf16 bf16;
typedef __bf16 bf16x8 __attribute__((ext_vector_type(8)));
typedef __bf16 bf16x4 __attribute__((ext_vector_type(4)));
typedef float f32x4 __attribute__((ext_vector_type(4)));

// ---------------- fp32 -> bf16 conversion ----------------
__global__ void cvt_f32_bf16(const float* __restrict__ in, bf16* __restrict__ out, int n) {
    int idx = (blockIdx.x * blockDim.x + threadIdx.x) * 4;
    if (idx < n) {
        float4 v = *(const float4*)(in + idx);
        bf16x4 o = { (bf16)v.x, (bf16)v.y, (bf16)v.z, (bf16)v.w };
        *(bf16x4*)(out + idx) = o;
    }
}

// 4 weight matrices in one dispatch (blockIdx.y selects)
__global__ void cvt_w4(const float* __restrict__ a, const float* __restrict__ b,
                       const float* __restrict__ c, const float* __restrict__ d,
                       bf16* __restrict__ oa, bf16* __restrict__ ob,
                       bf16* __restrict__ oc, bf16* __restrict__ od) {
    int idx = (blockIdx.x * blockDim.x + threadIdx.x) * 4;
    const float* in; bf16* out;
    switch (blockIdx.y) {
        case 0: in = a; out = oa; break;
        case 1: in = b; out = ob; break;
        case 2: in = c; out = oc; break;
        default: in = d; out = od; break;
    }
    float4 v = *(const float4*)(in + idx);
    bf16x4 o = { (bf16)v.x, (bf16)v.y, (bf16)v.z, (bf16)v.w };
    *(bf16x4*)(out + idx) = o;
}

// ---------------- async global->LDS helper ----------------
__device__ __forceinline__ void gld_lds16(const bf16* g, bf16* l) {
    __builtin_amdgcn_global_load_lds((const __attribute__((address_space(1))) void*)g,
                                     (__attribute__((address_space(3))) void*)l, 16, 0, 0);
}

// ---------------- GEMM: C[M,N] = A[M,K] * Bt[N,K]^T ----------------
// 128x128 tile, 512 threads (8 waves, 2x4), BK=64, linear LDS + XOR granule
// swizzle (both-sides: inverse-swizzled global source for global_load_lds,
// swizzled ds_read). 16x16x32 bf16 MFMA, per-wave 64x32 output (acc 4x2).
template <typename OutT>
__global__ __launch_bounds__(512) void gemm_bt(const bf16* __restrict__ A,
                                               const bf16* __restrict__ Bt,
                                               OutT* __restrict__ C,
                                               int M, int N, int K) {
    __shared__ bf16 As[128 * 64];
    __shared__ bf16 Bs[128 * 64];
    const int tid = threadIdx.x;
    const int bm = blockIdx.y * 128, bn = blockIdx.x * 128;
    const int w = tid >> 6, l = tid & 63;
    const int wr = w >> 2, wc = w & 3;     // 2 x 4 wave grid
    const int lr = l & 15, lc = l >> 4;

    // staging: wave w, call c covers rows [w*16 + c*8, +8). Lane i -> phys
    // granule i&7 of row w*16+c*8+(i>>3); logical granule = (i&7) ^ (row&7).
    const int srow = l >> 3;               // 0..7
    const int gl = (l & 7) ^ srow;         // row&7 == srow for all calls
    const bf16* Ag = A  + (size_t)(bm + w * 16 + srow) * K + gl * 8;
    const bf16* Bg = Bt + (size_t)(bn + w * 16 + srow) * K + gl * 8;

    f32x4 acc[4][2] = {};

    for (int k0 = 0; k0 < K; k0 += 64) {
        __syncthreads();
#pragma unroll
        for (int c = 0; c < 2; c++) {
            gld_lds16(Ag + (size_t)(c * 8) * K + k0, &As[(w * 16 + c * 8) * 64]);
            gld_lds16(Bg + (size_t)(c * 8) * K + k0, &Bs[(w * 16 + c * 8) * 64]);
        }
        __syncthreads();
#pragma unroll
        for (int s = 0; s < 2; s++) {
            bf16x8 af[4], bfr[2];
#pragma unroll
            for (int i = 0; i < 4; i++) {
                const int R = wr * 64 + i * 16 + lr;
                af[i] = *(bf16x8*)&As[R * 64 + (((s * 4 + lc) ^ (R & 7)) * 8)];
            }
#pragma unroll
            for (int j = 0; j < 2; j++) {
                const int R = wc * 32 + j * 16 + lr;
                bfr[j] = *(bf16x8*)&Bs[R * 64 + (((s * 4 + lc) ^ (R & 7)) * 8)];
            }
#pragma unroll
            for (int i = 0; i < 4; i++)
#pragma unroll
                for (int j = 0; j < 2; j++)
                    acc[i][j] = __builtin_amdgcn_mfma_f32_16x16x32_bf16(af[i], bfr[j], acc[i][j], 0, 0, 0);
        }
    }

    // C/D layout: col = lane&15, row = (lane>>4)*4 + reg
    const int cr = (l >> 4) * 4, cc = l & 15;
#pragma unroll
    for (int i = 0; i < 4; i++)
#pragma unroll
        for (int j = 0; j < 2; j++)
#pragma unroll
            for (int r = 0; r < 4; r++) {
                int row = bm + wr * 64 + i * 16 + cr + r;
                int col = bn + wc * 32 + j * 16 + cc;
                C[(size_t)row * N + col] = (OutT)acc[i][j][r];
            }
}

// ---------------- RoPE (in place, on (B,S,H,DK) == (B,S,D) layout) ----------------
__global__ void rope_k(bf16* __restrict__ Q, bf16* __restrict__ K) {
    int i = blockIdx.x * blockDim.x + threadIdx.x;  // over B*S*H*(DK/2) = 2^21
    int pair = i & 31;
    int h = (i >> 5) & 15;
    int s = (i >> 9) & 2047;
    int b = i >> 20;
    float inv_freq = __powf(10000.0f, -((2.0f * pair) / 64.0f));
    float ang = (float)s * inv_freq;
    float c = cosf(ang), sn = sinf(ang);
    size_t base = ((size_t)(b * Sc + s)) * Dc + h * 64 + pair * 2;
    float q1 = (float)Q[base], q2 = (float)Q[base + 1];
    Q[base]     = (bf16)(q1 * c - q2 * sn);
    Q[base + 1] = (bf16)(q1 * sn + q2 * c);
    float k1 = (float)K[base], k2 = (float)K[base + 1];
    K[base]     = (bf16)(k1 * c - k2 * sn);
    K[base + 1] = (bf16)(k1 * sn + k2 * c);
}

// ---------------- causal flash attention ----------------
// Per block: one (b, h, 64 q-rows). 4 waves x 16 q-rows. K-tiles of 64.
// Fixed-max softmax (scores clipped to +-80 then /8 => s <= 10, use p=exp(s-10);
// exact after normalization). Double-buffered K/V LDS, reg-prefetch staging
// (T14), 1 barrier/iter. Longest-first block order.
#define LDA 72  // LDS row stride (144B: 16B-aligned)
__global__ __launch_bounds__(256) void attn_k(const bf16* __restrict__ Q,
                                              const bf16* __restrict__ Kt,
                                              const bf16* __restrict__ V,
                                              bf16* __restrict__ Oa) {
    __shared__ bf16 Ks[2][64 * LDA];    // Ks[buf][key][dk]
    __shared__ bf16 Vs[2][64 * LDA];    // Vs[buf][dk][key] (transposed)
    __shared__ bf16 Ps[4][16 * LDA];    // per-wave P (no cross-wave use)

    const int bid = blockIdx.x;
    const int qi = 31 - (bid >> 5);     // longest blocks dispatched first
    const int bh = bid & 31;
    const int h = bh & 15, b = bh >> 4;
    const int q0 = qi * 64;
    const int tid = threadIdx.x, w = tid >> 6, l = tid & 63;
    const int lr = l & 15, lc = l >> 4;

    const bf16* Qb = Q  + ((size_t)b * Sc) * Dc + h * 64;
    const bf16* Kb = Kt + ((size_t)b * Sc) * Dc + h * 64;
    const bf16* Vb = V  + ((size_t)b * Sc) * Dc + h * 64;

    // Q fragments (hoisted): wave rows q0 + w*16 + lr
    const int qrow = q0 + w * 16 + lr;
    bf16x8 qf0 = *(const bf16x8*)(Qb + (size_t)qrow * Dc + lc * 8);
    bf16x8 qf1 = *(const bf16x8*)(Qb + (size_t)qrow * Dc + 32 + lc * 8);

    f32x4 oacc[4] = {};
    float psum[4] = {0.f, 0.f, 0.f, 0.f};

    const int nt = qi + 1;
    const int skey = tid >> 3, sdk = (tid & 7) * 8;
    const int vkey = tid & 63, vdk0 = (tid >> 6) * 16;

    bf16x8 kr0, kr1, vr0, vr1;
#define LOADT(T) { const size_t kk = (size_t)(T) * 64;                          \
        kr0 = *(const bf16x8*)(Kb + (kk + skey) * Dc + sdk);                    \
        kr1 = *(const bf16x8*)(Kb + (kk + skey + 32) * Dc + sdk);               \
        vr0 = *(const bf16x8*)(Vb + (kk + vkey) * Dc + vdk0);                   \
        vr1 = *(const bf16x8*)(Vb + (kk + vkey) * Dc + vdk0 + 8); }
#define WRITET(BUF) {                                                           \
        *(bf16x8*)&Ks[BUF][skey * LDA + sdk] = kr0;                             \
        *(bf16x8*)&Ks[BUF][(skey + 32) * LDA + sdk] = kr1;                      \
        _Pragma("unroll") for (int e = 0; e < 8; e++) {                         \
            Vs[BUF][(vdk0 + e) * LDA + vkey] = vr0[e];                          \
            Vs[BUF][(vdk0 + 8 + e) * LDA + vkey] = vr1[e]; } }

    LOADT(0); WRITET(0);
    int cur = 0;
    for (int t = 0; t < nt; t++) {
        const int k0 = t * 64;
        if (t + 1 < nt) LOADT(t + 1);   // async: in flight under compute
        __syncthreads();                // buf[cur] (written last iter) visible

        // S = Q K^T  (per wave: 16 q-rows x 64 keys)
        f32x4 sfr[4];
#pragma unroll
        for (int j = 0; j < 4; j++) {
            bf16x8 b0 = *(bf16x8*)&Ks[cur][(j * 16 + lr) * LDA + lc * 8];
            bf16x8 b1 = *(bf16x8*)&Ks[cur][(j * 16 + lr) * LDA + 32 + lc * 8];
            f32x4 z = {};
            z = __builtin_amdgcn_mfma_f32_16x16x32_bf16(qf0, b0, z, 0, 0, 0);
            z = __builtin_amdgcn_mfma_f32_16x16x32_bf16(qf1, b1, z, 0, 0, 0);
            sfr[j] = z;
        }

        // fixed-max softmax: p = exp(clip(s)/8 - 10); only diagonal tile masked
        const bool diag = (t == nt - 1);
#pragma unroll
        for (int j = 0; j < 4; j++) {
            const int kg = k0 + j * 16 + lr;
#pragma unroll
            for (int r = 0; r < 4; r++) {
                float s = sfr[j][r];
                s = fminf(fmaxf(s, -80.0f), 80.0f) * 0.125f;
                float p = __expf(s - 10.0f);
                if (diag && kg > (q0 + w * 16 + lc * 4 + r)) p = 0.0f;
                psum[r] += p;
                Ps[w][(lc * 4 + r) * LDA + j * 16 + lr] = (bf16)p;
            }
        }

        // O += P V  (Ps is per-wave: no barrier, compiler inserts lgkmcnt)
#pragma unroll
        for (int c = 0; c < 2; c++) {
            bf16x8 pf = *(bf16x8*)&Ps[w][lr * LDA + c * 32 + lc * 8];
#pragma unroll
            for (int j = 0; j < 4; j++) {
                bf16x8 vf = *(bf16x8*)&Vs[cur][(j * 16 + lr) * LDA + c * 32 + lc * 8];
                oacc[j] = __builtin_amdgcn_mfma_f32_16x16x32_bf16(pf, vf, oacc[j], 0, 0, 0);
            }
        }

        if (t + 1 < nt) WRITET(cur ^ 1);  // other buffer; all waves crossed
        cur ^= 1;                          // this iter's barrier after last reads
    }

    // one reduction after the loop (not per tile): sum over the 16 lr lanes
#pragma unroll
    for (int d = 1; d < 16; d <<= 1)
#pragma unroll
        for (int r = 0; r < 4; r++) psum[r] += __shfl_xor(psum[r], d, 64);

    bf16* Ob = Oa + ((size_t)b * Sc) * Dc + h * 64;
#pragma unroll
    for (int j = 0; j < 4; j++)
#pragma unroll
        for (int r = 0; r < 4; r++) {
            int qg = q0 + w * 16 + lc * 4 + r;
            Ob[(size_t)qg * Dc + j * 16 + lr] = (bf16)(oacc[j][r] / psum[r]);
        }
}

// ---------------- launcher ----------------
extern "C" void kernel_launch(void* const* d_in, const int* in_sizes, int n_in,
                              void* d_out, int out_size, void* d_ws, size_t ws_size,
                              hipStream_t stream) {
    const float* x  = (const float*)d_in[0];
    const float* Wq = (const float*)d_in[1];
    const float* Wk = (const float*)d_in[2];
    const float* Wv = (const float*)d_in[3];
    const float* Wo = (const float*)d_in[4];

    const int NX = Bc * Sc * Dc;   // 4,194,304
    const int NW = Dc * Dc;        // 1,048,576

    bf16* xb  = (bf16*)d_ws;
    bf16* wqb = xb + NX;
    bf16* wkb = wqb + NW;
    bf16* wvb = wkb + NW;
    bf16* wob = wvb + NW;
    bf16* Yq  = wob + NW;
    bf16* Yk  = Yq + NX;
    bf16* Yv  = Yk + NX;
    bf16* att = Yv + NX;
    // total: 25,165,824 bf16 elems = 48 MiB of d_ws

    cvt_f32_bf16<<<NX / 4 / 256, 256, 0, stream>>>(x, xb, NX);
    cvt_w4<<<dim3(NW / 4 / 256, 4), 256, 0, stream>>>(Wq, Wk, Wv, Wo, wqb, wkb, wvb, wob);

    dim3 gg(Dc / 128, Mrows / 128);  // (8, 32)
    gemm_bt<bf16><<<gg, 512, 0, stream>>>(xb, wqb, Yq, Mrows, Dc, Dc);
    gemm_bt<bf16><<<gg, 512, 0, stream>>>(xb, wkb, Yk, Mrows, Dc, Dc);
    gemm_bt<bf16><<<gg, 512, 0, stream>>>(xb, wvb, Yv, Mrows, Dc, Dc);

    rope_k<<<(Bc * Sc * Hc * 32) / 256, 256, 0, stream>>>(Yq, Yk);

    attn_k<<<Bc * Hc * (Sc / 64), 256, 0, stream>>>(Yq, Yk, Yv, att);

    gemm_bt<float><<<gg, 512, 0, stream>>>(att, wob, (float*)d_out, Mrows, Dc, Dc);
}

// Round 4
// 188.210 us; speedup vs baseline: 1.8314x; 1.1821x over previous
//
#include <hip/hip_runtime.h>
#include <hip/hip_bf16.h>

// Problem constants
#define Bc 2
#define Sc 2048
#define Dc 1024
#define Hc 16
#define DKc 64
#define Mrows 4096   // B*S
#define QKV_LD 3072  // packed QKV row stride

typedef __bf16 bf16;
typedef __bf16 bf16x8 __attribute__((ext_vector_type(8)));
typedef __bf16 bf16x4 __attribute__((ext_vector_type(4)));
typedef float f32x4 __attribute__((ext_vector_type(4)));

// ---------------- fp32 -> bf16 conversion ----------------
__global__ void cvt_f32_bf16(const float* __restrict__ in, bf16* __restrict__ out, int n) {
    int idx = (blockIdx.x * blockDim.x + threadIdx.x) * 4;
    if (idx < n) {
        float4 v = *(const float4*)(in + idx);
        bf16x4 o = { (bf16)v.x, (bf16)v.y, (bf16)v.z, (bf16)v.w };
        *(bf16x4*)(out + idx) = o;
    }
}

__global__ void cvt_w4(const float* __restrict__ a, const float* __restrict__ b,
                       const float* __restrict__ c, const float* __restrict__ d,
                       bf16* __restrict__ oa, bf16* __restrict__ ob,
                       bf16* __restrict__ oc, bf16* __restrict__ od) {
    int idx = (blockIdx.x * blockDim.x + threadIdx.x) * 4;
    const float* in; bf16* out;
    switch (blockIdx.y) {
        case 0: in = a; out = oa; break;
        case 1: in = b; out = ob; break;
        case 2: in = c; out = oc; break;
        default: in = d; out = od; break;
    }
    float4 v = *(const float4*)(in + idx);
    bf16x4 o = { (bf16)v.x, (bf16)v.y, (bf16)v.z, (bf16)v.w };
    *(bf16x4*)(out + idx) = o;
}

// ---------------- async global->LDS helper ----------------
__device__ __forceinline__ void gld_lds16(const bf16* g, bf16* l) {
    __builtin_amdgcn_global_load_lds((const __attribute__((address_space(1))) void*)g,
                                     (__attribute__((address_space(3))) void*)l, 16, 0, 0);
}

__device__ __forceinline__ unsigned bperm(int addrBytes, unsigned v) {
    return (unsigned)__builtin_amdgcn_ds_bpermute(addrBytes, (int)v);
}

// ---------------- GEMM: C[M,N] = A[M,K] * Bt[N,K]^T ----------------
// 128x128 tile, 512 threads (8 waves, 2x4), BK=64, linear LDS + XOR granule
// swizzle (both-sides). 16x16x32 bf16 MFMA, per-wave 64x32 output.
template <typename OutT>
__global__ __launch_bounds__(512) void gemm_bt(const bf16* __restrict__ A,
                                               const bf16* __restrict__ Bt,
                                               OutT* __restrict__ C,
                                               int M, int N, int K) {
    __shared__ bf16 As[128 * 64];
    __shared__ bf16 Bs[128 * 64];
    const int tid = threadIdx.x;
    const int bm = blockIdx.y * 128, bn = blockIdx.x * 128;
    const int w = tid >> 6, l = tid & 63;
    const int wr = w >> 2, wc = w & 3;
    const int lr = l & 15, lc = l >> 4;

    const int srow = l >> 3;
    const int gl = (l & 7) ^ srow;
    const bf16* Ag = A  + (size_t)(bm + w * 16 + srow) * K + gl * 8;
    const bf16* Bg = Bt + (size_t)(bn + w * 16 + srow) * K + gl * 8;

    f32x4 acc[4][2] = {};

    for (int k0 = 0; k0 < K; k0 += 64) {
        __syncthreads();
#pragma unroll
        for (int c = 0; c < 2; c++) {
            gld_lds16(Ag + (size_t)(c * 8) * K + k0, &As[(w * 16 + c * 8) * 64]);
            gld_lds16(Bg + (size_t)(c * 8) * K + k0, &Bs[(w * 16 + c * 8) * 64]);
        }
        __syncthreads();
#pragma unroll
        for (int s = 0; s < 2; s++) {
            bf16x8 af[4], bfr[2];
#pragma unroll
            for (int i = 0; i < 4; i++) {
                const int R = wr * 64 + i * 16 + lr;
                af[i] = *(bf16x8*)&As[R * 64 + (((s * 4 + lc) ^ (R & 7)) * 8)];
            }
#pragma unroll
            for (int j = 0; j < 2; j++) {
                const int R = wc * 32 + j * 16 + lr;
                bfr[j] = *(bf16x8*)&Bs[R * 64 + (((s * 4 + lc) ^ (R & 7)) * 8)];
            }
#pragma unroll
            for (int i = 0; i < 4; i++)
#pragma unroll
                for (int j = 0; j < 2; j++)
                    acc[i][j] = __builtin_amdgcn_mfma_f32_16x16x32_bf16(af[i], bfr[j], acc[i][j], 0, 0, 0);
        }
    }

    const int cr = (l >> 4) * 4, cc = l & 15;
#pragma unroll
    for (int i = 0; i < 4; i++)
#pragma unroll
        for (int j = 0; j < 2; j++)
#pragma unroll
            for (int r = 0; r < 4; r++) {
                int row = bm + wr * 64 + i * 16 + cr + r;
                int col = bn + wc * 32 + j * 16 + cc;
                C[(size_t)row * N + col] = (OutT)acc[i][j][r];
            }
}

// ---------------- RoPE (in place on packed QKV; Q at col 0, K at col 1024) ----------------
__global__ void rope_k(bf16* __restrict__ QKV) {
    int i = blockIdx.x * blockDim.x + threadIdx.x;  // B*S*H*(DK/2) = 2^21
    int pair = i & 31;
    int h = (i >> 5) & 15;
    int s = (i >> 9) & 2047;
    int b = i >> 20;
    float inv_freq = exp2f(-0.41524101186f * (float)pair);  // 10000^(-2p/64)
    float ang = (float)s * inv_freq;
    float c = cosf(ang), sn = sinf(ang);
    size_t base = ((size_t)(b * Sc + s)) * QKV_LD + h * 64 + pair * 2;
    float q1 = (float)QKV[base], q2 = (float)QKV[base + 1];
    QKV[base]     = (bf16)(q1 * c - q2 * sn);
    QKV[base + 1] = (bf16)(q1 * sn + q2 * c);
    size_t kb = base + 1024;
    float k1 = (float)QKV[kb], k2 = (float)QKV[kb + 1];
    QKV[kb]     = (bf16)(k1 * c - k2 * sn);
    QKV[kb + 1] = (bf16)(k1 * sn + k2 * c);
}

// ---------------- V transpose: QKV V-cols -> Vt[(b*H+h)*64+dk][s] ----------------
// LDS stride 68 elems: b64-aligned rows, 2-way-max banks on column gather.
__global__ __launch_bounds__(256) void vtrans(const bf16* __restrict__ QKV, bf16* __restrict__ Vt) {
    __shared__ bf16 T[64 * 68];
    const int s0 = blockIdx.x * 64;
    const int bh = blockIdx.y;
    const int b = bh >> 4, h = bh & 15;
    const int tid = threadIdx.x;
    const bf16* src = QKV + (size_t)(b * Sc + s0) * QKV_LD + 2048 + h * 64;
#pragma unroll
    for (int p = 0; p < 2; p++) {
        int sr = (tid >> 3) + p * 32;
        int dk0 = (tid & 7) * 8;
        bf16x8 v = *(const bf16x8*)(src + (size_t)sr * QKV_LD + dk0);
        bf16x4 lo = { v[0], v[1], v[2], v[3] }, hi = { v[4], v[5], v[6], v[7] };
        *(bf16x4*)&T[sr * 68 + dk0]     = lo;
        *(bf16x4*)&T[sr * 68 + dk0 + 4] = hi;
    }
    __syncthreads();
    bf16* dst = Vt + (size_t)(bh * 64) * Sc + s0;
#pragma unroll
    for (int p = 0; p < 2; p++) {
        int dk = (tid >> 3) + p * 32;
        int sc0 = (tid & 7) * 8;
        bf16x8 v;
#pragma unroll
        for (int e = 0; e < 8; e++) v[e] = T[(sc0 + e) * 68 + dk];
        *(bf16x8*)(dst + (size_t)dk * Sc + sc0) = v;
    }
}

// ---------------- causal flash attention ----------------
// Per block: (b,h,64 q-rows); 4 waves x 16 q. Swapped QK^T (P lane-local),
// fixed-max softmax, bpermute P-exchange, global_load_lds staging with
// granule-XOR swizzle, double-buffered, counted vmcnt prefetch.
__global__ __launch_bounds__(256) void attn_k(const bf16* __restrict__ QKV,
                                              const bf16* __restrict__ Vt,
                                              bf16* __restrict__ Oa) {
    __shared__ bf16 Ks[2][64 * 64];   // [key][dk] granule-swizzled
    __shared__ bf16 Vs[2][64 * 64];   // [dk][key] granule-swizzled

    const int bid = blockIdx.x;
    const int qi = 31 - (bid >> 5);   // longest-first
    const int bh = bid & 31;
    const int h = bh & 15, b = bh >> 4;
    const int q0 = qi * 64;
    const int tid = threadIdx.x, w = tid >> 6, l = tid & 63;
    const int lr = l & 15, lc = l >> 4;

    const bf16* Qb  = QKV + (size_t)(b * Sc) * QKV_LD + h * 64;
    const bf16* Kb  = QKV + (size_t)(b * Sc) * QKV_LD + 1024 + h * 64;
    const bf16* Vtb = Vt + (size_t)(bh * 64) * Sc;

    // Q fragments (hoisted): wave rows q0 + w*16 + lr
    const int qrow = q0 + w * 16 + lr;
    bf16x8 qf0 = *(const bf16x8*)(Qb + (size_t)qrow * QKV_LD + lc * 8);
    bf16x8 qf1 = *(const bf16x8*)(Qb + (size_t)qrow * QKV_LD + 32 + lc * 8);

    // staging geometry: lane -> row r8, phys granule l&7, logical gl
    const int r8 = l >> 3, glg = (l & 7) ^ r8;
    const bf16* Kg = Kb  + (size_t)(16 * w + r8) * QKV_LD + glg * 8;
    const bf16* Vg = Vtb + (size_t)(16 * w + r8) * Sc + glg * 8;

    f32x4 oacc[4] = {};
    float psum = 0.f;

    // bpermute byte addrs (constant per lane): sources for P exchange
    const int sA = (lr + ((lc & 1) << 5)) << 2;
    const int sB = sA + (16 << 2);
    const bool hij = (lc & 2) != 0;   // selects j = 2c + (lc>>1)

    const int nt = qi + 1;
    int cur = 0;

#define STAGE(T, BUF) {                                                            \
    const size_t kof = (size_t)((T) * 64) * QKV_LD;                                \
    const size_t vof = (size_t)((T) * 64);                                         \
    gld_lds16(Kg + kof,                    &Ks[BUF][(16 * w) * 64]);               \
    gld_lds16(Kg + kof + (size_t)8 * QKV_LD, &Ks[BUF][(16 * w + 8) * 64]);         \
    gld_lds16(Vg + vof,                    &Vs[BUF][(16 * w) * 64]);               \
    gld_lds16(Vg + vof + (size_t)8 * Sc,   &Vs[BUF][(16 * w + 8) * 64]); }

    STAGE(0, 0);
    for (int t = 0; t < nt; t++) {
        const int k0 = t * 64;
        if (t + 1 < nt) {
            __builtin_amdgcn_s_barrier();              // prev reads of buf[cur^1] done
            STAGE(t + 1, cur ^ 1);
            asm volatile("s_waitcnt vmcnt(4)" ::: "memory");  // tile t landed; t+1 in flight
        } else {
            asm volatile("s_waitcnt vmcnt(0)" ::: "memory");
        }
        __builtin_amdgcn_s_barrier();                  // all waves' tile-t staging visible

        // QK^T swapped: sfr[j] = S^T (col=q=lr, row=key=16j+4lc+r)
        f32x4 sfr[4];
#pragma unroll
        for (int j = 0; j < 4; j++) {
            const int R = j * 16 + lr;
            bf16x8 kf0 = *(bf16x8*)&Ks[cur][R * 64 + ((lc ^ (lr & 7)) * 8)];
            bf16x8 kf1 = *(bf16x8*)&Ks[cur][R * 64 + (((4 + lc) ^ (lr & 7)) * 8)];
            f32x4 z = {};
            z = __builtin_amdgcn_mfma_f32_16x16x32_bf16(kf0, qf0, z, 0, 0, 0);
            z = __builtin_amdgcn_mfma_f32_16x16x32_bf16(kf1, qf1, z, 0, 0, 0);
            sfr[j] = z;
        }

        // fixed-max softmax: p = exp(clip(s)/8 - 10), exact after normalization
        const bool diag = (t == nt - 1);
        const int qg = q0 + w * 16 + lr;
        float pv[4][4];
#pragma unroll
        for (int j = 0; j < 4; j++)
#pragma unroll
            for (int r = 0; r < 4; r++) {
                float s = fminf(fmaxf(sfr[j][r], -80.f), 80.f);
                float p = __expf(s * 0.125f - 10.0f);
                if (diag && (k0 + j * 16 + lc * 4 + r) > qg) p = 0.f;
                psum += p;
                pv[j][r] = p;
            }

        // pack to bf16x2 words: w0[j]=(r0,r1), w1[j]=(r2,r3)
        unsigned pw0[4], pw1[4];
#pragma unroll
        for (int j = 0; j < 4; j++) {
            asm("v_cvt_pk_bf16_f32 %0, %1, %2" : "=v"(pw0[j]) : "v"(pv[j][0]), "v"(pv[j][1]));
            asm("v_cvt_pk_bf16_f32 %0, %1, %2" : "=v"(pw1[j]) : "v"(pv[j][2]), "v"(pv[j][3]));
        }

        // exchange -> PV A-frags: pa[c] elems e: P[q=lr][key=c*32+8lc+e]
        union { int4 i; bf16x8 h; } u0, u1;
        {
            unsigned t0 = bperm(sA, pw0[0]), s0_ = bperm(sA, pw0[1]);
            unsigned t1 = bperm(sA, pw1[0]), s1_ = bperm(sA, pw1[1]);
            unsigned t2 = bperm(sB, pw0[0]), s2_ = bperm(sB, pw0[1]);
            unsigned t3 = bperm(sB, pw1[0]), s3_ = bperm(sB, pw1[1]);
            u0.i = (int4){ (int)(hij ? s0_ : t0), (int)(hij ? s1_ : t1),
                           (int)(hij ? s2_ : t2), (int)(hij ? s3_ : t3) };
            unsigned v0 = bperm(sA, pw0[2]), r0_ = bperm(sA, pw0[3]);
            unsigned v1 = bperm(sA, pw1[2]), r1_ = bperm(sA, pw1[3]);
            unsigned v2 = bperm(sB, pw0[2]), r2_ = bperm(sB, pw0[3]);
            unsigned v3 = bperm(sB, pw1[2]), r3_ = bperm(sB, pw1[3]);
            u1.i = (int4){ (int)(hij ? r0_ : v0), (int)(hij ? r1_ : v1),
                           (int)(hij ? r2_ : v2), (int)(hij ? r3_ : v3) };
        }

        // O += P V : B-frag from Vs[dk][key] (col=dk=16jd+lr, k=key)
#pragma unroll
        for (int jd = 0; jd < 4; jd++) {
            const int R = jd * 16 + lr;
            bf16x8 vf0 = *(bf16x8*)&Vs[cur][R * 64 + ((lc ^ (lr & 7)) * 8)];
            bf16x8 vf1 = *(bf16x8*)&Vs[cur][R * 64 + (((4 + lc) ^ (lr & 7)) * 8)];
            oacc[jd] = __builtin_amdgcn_mfma_f32_16x16x32_bf16(u0.h, vf0, oacc[jd], 0, 0, 0);
            oacc[jd] = __builtin_amdgcn_mfma_f32_16x16x32_bf16(u1.h, vf1, oacc[jd], 0, 0, 0);
        }
        cur ^= 1;
    }

    // row-sum finish: reduce psum across the 4 lc groups, redistribute to O layout
    psum += __shfl_xor(psum, 16, 64);
    psum += __shfl_xor(psum, 32, 64);
    float pr[4];
#pragma unroll
    for (int r = 0; r < 4; r++) pr[r] = __shfl(psum, lc * 4 + r, 64);

    bf16* Ob = Oa + (size_t)(b * Sc) * Dc + h * 64;
#pragma unroll
    for (int jd = 0; jd < 4; jd++)
#pragma unroll
        for (int r = 0; r < 4; r++) {
            int qg2 = q0 + w * 16 + lc * 4 + r;
            Ob[(size_t)qg2 * Dc + jd * 16 + lr] = (bf16)(oacc[jd][r] / pr[r]);
        }
#undef STAGE
}

// ---------------- launcher ----------------
extern "C" void kernel_launch(void* const* d_in, const int* in_sizes, int n_in,
                              void* d_out, int out_size, void* d_ws, size_t ws_size,
                              hipStream_t stream) {
    const float* x  = (const float*)d_in[0];
    const float* Wq = (const float*)d_in[1];
    const float* Wk = (const float*)d_in[2];
    const float* Wv = (const float*)d_in[3];
    const float* Wo = (const float*)d_in[4];

    const int NX = Bc * Sc * Dc;   // 4,194,304
    const int NW = Dc * Dc;        // 1,048,576

    bf16* xb   = (bf16*)d_ws;          // also reused as att output
    bf16* wqb  = xb + NX;              // wq,wk,wv contiguous = packed B^T [3072][1024]
    bf16* wkb  = wqb + NW;
    bf16* wvb  = wkb + NW;
    bf16* wob  = wvb + NW;
    bf16* QKV  = wob + NW;             // [4096][3072]
    bf16* Vt   = QKV + (size_t)Mrows * QKV_LD;  // [32*64][2048]
    bf16* att  = xb;
    // end = 25,165,824 elems = 48 MiB

    cvt_f32_bf16<<<NX / 4 / 256, 256, 0, stream>>>(x, xb, NX);
    cvt_w4<<<dim3(NW / 4 / 256, 4), 256, 0, stream>>>(Wq, Wk, Wv, Wo, wqb, wkb, wvb, wob);

    gemm_bt<bf16><<<dim3(QKV_LD / 128, Mrows / 128), 512, 0, stream>>>(xb, wqb, QKV, Mrows, QKV_LD, Dc);

    rope_k<<<(Bc * Sc * Hc * 32) / 256, 256, 0, stream>>>(QKV);
    vtrans<<<dim3(Sc / 64, Bc * Hc), 256, 0, stream>>>(QKV, Vt);

    attn_k<<<Bc * Hc * (Sc / 64), 256, 0, stream>>>(QKV, Vt, att);

    gemm_bt<float><<<dim3(Dc / 128, Mrows / 128), 512, 0, stream>>>(att, wob, (float*)d_out, Mrows, Dc, Dc);
}